// Round 3
// baseline (36.467 us; speedup 1.0000x reference)
//
#include <hip/hip_runtime.h>
#include <math.h>

#define TPB 256
#define NQ 4                 // matrices per thread (4 independent chains)
#define MPB (TPB * NQ)       // matrices per block

typedef float v4  __attribute__((ext_vector_type(4)));
typedef int   v4i __attribute__((ext_vector_type(4)));

static __device__ __forceinline__ v4 V4(float x){ v4 r; r.x=x; r.y=x; r.z=x; r.w=x; return r; }
static __device__ __forceinline__ v4 vfma(v4 a, v4 b, v4 c){ return __builtin_elementwise_fma(a, b, c); }
static __device__ __forceinline__ v4 vmax(v4 a, v4 b){ return __builtin_elementwise_max(a, b); }
static __device__ __forceinline__ v4 vabs(v4 a){ return __builtin_elementwise_abs(a); }
static __device__ __forceinline__ v4 vcps(v4 a, v4 b){ return __builtin_elementwise_copysign(a, b); }

// per-component transcendentals (no packed variants; 4 independent ops = ILP)
static __device__ __forceinline__ v4 rsq4(v4 x){
  v4 r; r.x=__builtin_amdgcn_rsqf(x.x); r.y=__builtin_amdgcn_rsqf(x.y);
        r.z=__builtin_amdgcn_rsqf(x.z); r.w=__builtin_amdgcn_rsqf(x.w); return r; }
static __device__ __forceinline__ v4 rcp4(v4 x){
  v4 r; r.x=__builtin_amdgcn_rcpf(x.x); r.y=__builtin_amdgcn_rcpf(x.y);
        r.z=__builtin_amdgcn_rcpf(x.z); r.w=__builtin_amdgcn_rcpf(x.w); return r; }
static __device__ __forceinline__ v4 sqt4(v4 x){
  v4 r; r.x=__builtin_amdgcn_sqrtf(x.x); r.y=__builtin_amdgcn_sqrtf(x.y);
        r.z=__builtin_amdgcn_sqrtf(x.z); r.w=__builtin_amdgcn_sqrtf(x.w); return r; }
static __device__ __forceinline__ v4 lg24(v4 x){
  v4 r; r.x=__builtin_amdgcn_logf(x.x); r.y=__builtin_amdgcn_logf(x.y);
        r.z=__builtin_amdgcn_logf(x.z); r.w=__builtin_amdgcn_logf(x.w); return r; }
static __device__ __forceinline__ v4 ex24(v4 x){
  v4 r; r.x=__builtin_amdgcn_exp2f(x.x); r.y=__builtin_amdgcn_exp2f(x.y);
        r.z=__builtin_amdgcn_exp2f(x.z); r.w=__builtin_amdgcn_exp2f(x.w); return r; }

// elementwise select: m ? a : b  (m is -1/0 per component from a vector compare)
static __device__ __forceinline__ v4 vsel(v4i m, v4 a, v4 b){
  v4i ai = __builtin_bit_cast(v4i, a), bi = __builtin_bit_cast(v4i, b);
  return __builtin_bit_cast(v4, (ai & m) | (bi & ~m));
}

// Exact Jacobi rotation for [[app,apq],[apq,aqq]] via half-angle form.
// Clamp 1e-30f is a REPRESENTABLE normal float (1e-60 rounds to 0!): the
// degenerate d=apq=0 case resolves to the identity rotation, NaN-free.
__device__ __forceinline__ void jcs2(v4 app_in, v4 aqq_in, v4 apq,
                                     v4& c, v4& s,
                                     v4& app_out, v4& aqq_out)
{
  v4 d    = (aqq_in - app_in) * 0.5f;
  v4 r2   = vmax(vfma(d, d, apq * apq), V4(1e-30f));
  v4 invh = rsq4(r2);
  v4 h    = r2 * invh;                       // sqrt(d^2 + apq^2)
  v4 sg   = vcps(V4(1.0f), d);
  v4 ch   = h + vabs(d);
  v4 sh   = apq * sg;
  v4 w    = rsq4(vfma(ch, ch, sh * sh));
  c = ch * w;
  s = sh * w;
  v4 hs = h * sg;
  v4 m  = app_in + d;                        // (app+aqq)/2
  app_out = m - hs;
  aqq_out = m + hs;
}

// Full rotation: diag (closed form), third-index couplings, V columns p,q.
__device__ __forceinline__ void jrot(v4& app, v4& aqq, v4& apq,
                                     v4& apk, v4& aqk,
                                     v4& vp0, v4& vp1, v4& vp2,
                                     v4& vq0, v4& vq1, v4& vq2)
{
  v4 c, s;
  jcs2(app, aqq, apq, c, s, app, aqq);   // inputs by value: aliasing safe
  apq = V4(0.0f);
  v4 pk = apk, qk = aqk;
  apk = c * pk - s * qk;
  aqk = s * pk + c * qk;
  v4 v;
  v = vp0; vp0 = c*v - s*vq0; vq0 = s*v + c*vq0;
  v = vp1; vp1 = c*v - s*vq1; vq1 = s*v + c*vq1;
  v = vp2; vp2 = c*v - s*vq2; vq2 = s*v + c*vq2;
}

// Compare-swap: per-component (the 4 matrices in a thread sort independently).
#define CSWAP(li, lj, a0, a1, a2, b0, b1, b2)                                   \
  do {                                                                          \
    v4i _m = (li) < (lj);                                                       \
    v4 _t;                                                                      \
    _t = vsel(_m,(lj),(li)); (lj) = vsel(_m,(li),(lj)); (li) = _t;              \
    _t = vsel(_m,(b0),(a0)); (b0) = vsel(_m,(a0),(b0)); (a0) = _t;              \
    _t = vsel(_m,(b1),(a1)); (b1) = vsel(_m,(a1),(b1)); (a1) = _t;              \
    _t = vsel(_m,(b2),(a2)); (b2) = vsel(_m,(a2),(b2)); (a2) = _t;              \
  } while (0)

__global__ __launch_bounds__(TPB) void plastic_svd_kernel(
    const float* __restrict__ F,
    const float* __restrict__ p_yml,
    const float* __restrict__ p_nu,
    const float* __restrict__ p_ys,
    float* __restrict__ out,
    int nmat)
{
  __shared__ float lds[MPB * 9];
  const int tid = threadIdx.x;
  const int blockBase = blockIdx.x * MPB;
  const int gbase = blockBase * 9;
  const int rem = nmat - blockBase;
  const int nfl = (rem >= MPB ? MPB : rem) * 9;
  const int nfl4 = nfl >> 2;

  // coalesced global -> LDS stage, float4-wide (gbase*4 bytes is 16B-aligned)
  {
    const float4* g4 = (const float4*)(F + gbase);
    float4* l4 = (float4*)lds;
    #pragma unroll
    for (int k = 0; k < 9; ++k) {            // 9*256 = 2304 = MPB*9/4
      int i4 = k * TPB + tid;
      if (i4 < nfl4) l4[i4] = g4[i4];
    }
    int i = (nfl & ~3) + tid;
    if (i < nfl) lds[i] = F[gbase + i];      // scalar tail (<=3 elems)
    // zero-fill inactive tail (last block only); with the 1e-30 clamps the
    // zero matrix runs NaN-free through the whole pipeline.
    for (int i2 = nfl + tid; i2 < MPB * 9; i2 += TPB) lds[i2] = 0.0f;
  }
  __syncthreads();

  // Thread q-slot matrices at (q*TPB + tid): stride-9 LDS reads are
  // conflict-free (gcd(9,32)=1). Chunk ownership exclusive per-thread ->
  // F persists in LDS until this thread overwrites it with its own output.

  // ---- S = F^T F from LDS; F registers die after (VGPR relief in Jacobi) ----
  v4 s00, s11, s22, s01, s02, s12;
  {
    v4 f00,f01,f02,f10,f11,f12,f20,f21,f22;
    #pragma unroll
    for (int q = 0; q < NQ; ++q) {
      const float* m = &lds[(q * TPB + tid) * 9];
      f00[q]=m[0]; f01[q]=m[1]; f02[q]=m[2];
      f10[q]=m[3]; f11[q]=m[4]; f12[q]=m[5];
      f20[q]=m[6]; f21[q]=m[7]; f22[q]=m[8];
    }
    s00 = f00*f00 + f10*f10 + f20*f20;
    s11 = f01*f01 + f11*f11 + f21*f21;
    s22 = f02*f02 + f12*f12 + f22*f22;
    s01 = f00*f01 + f10*f11 + f20*f21;
    s02 = f00*f02 + f10*f12 + f20*f22;
    s12 = f01*f02 + f11*f12 + f21*f22;
  }

  // uniform scalar parameters (once per thread, amortized over 4 matrices)
  const float mu_s = __builtin_amdgcn_exp2f(p_yml[0] * 1.44269504f) *
                     __builtin_amdgcn_rcpf(2.0f * (1.0f + p_nu[0]));
  const float qy_s = p_ys[0] * 0.5f * __builtin_amdgcn_rcpf(mu_s);
  const v4 qy = V4(qy_s);

  v4 v00,v01,v02,v10,v11,v12,v20,v21,v22;
  v4 c, s;

  // ---- sweep 1, rot (0,1): V = I specialization ----
  jcs2(s00, s11, s01, c, s, s00, s11);
  { v4 pk = s02, qk = s12; s02 = c*pk - s*qk; s12 = s*pk + c*qk; }
  v00 = c;  v01 = s;
  v10 = -s; v11 = c;
  s01 = V4(0.0f);
  // ---- sweep 1, rot (0,2): col2 still e3, col0 = (v00,v10,0) ----
  jcs2(s00, s22, s02, c, s, s00, s22);
  { v4 pk = s01, qk = s12; s01 = c*pk - s*qk; s12 = s*pk + c*qk; }
  v02 = s * v00; v12 = s * v10; v22 = c;   // vq' = s*vp + c*e3 (old vp)
  v00 = c * v00; v10 = c * v10; v20 = -s;  // vp' = c*vp - s*e3
  v21 = V4(0.0f);
  s02 = V4(0.0f);
  // ---- sweep 1, rot (1,2) ----
  jrot(s11, s22, s12, s01, s02, v01, v11, v21, v02, v12, v22);
  // ---- sweep 2 ----
  jrot(s00, s11, s01, s02, s12, v00, v10, v20, v01, v11, v21);
  jrot(s00, s22, s02, s01, s12, v00, v10, v20, v02, v12, v22);
  jrot(s11, s22, s12, s01, s02, v01, v11, v21, v02, v12, v22);
  // ---- sweep 3 ----
  jrot(s00, s11, s01, s02, s12, v00, v10, v20, v01, v11, v21);
  jrot(s00, s22, s02, s01, s12, v00, v10, v20, v02, v12, v22);
  // final rot (1,2): couplings dead; diag still updated (closed form, cheap).
  jcs2(s11, s22, s12, c, s, s11, s22);
  { v4 v;
    v = v01; v01 = c*v - s*v02; v02 = s*v + c*v02;
    v = v11; v11 = c*v - s*v12; v12 = s*v + c*v12;
    v = v21; v21 = c*v - s*v22; v22 = s*v + c*v22; }

  // ---- sort eigenvalues descending, V columns along ----
  // Sort is REQUIRED: Gram-Schmidt U-construction below is conditioned only
  // when v0 belongs to the largest sigma. (R2 lesson: never divide by the
  // smallest sigma -- u2 must come from the cross product.)
  v4 l0 = s00, l1 = s11, l2 = s22;
  CSWAP(l0, l1, v00, v10, v20, v01, v11, v21);
  CSWAP(l1, l2, v01, v11, v21, v02, v12, v22);
  CSWAP(l0, l1, v00, v10, v20, v01, v11, v21);

  // ---- re-read F from LDS (still intact: own chunks) ----
  v4 f00,f01,f02,f10,f11,f12,f20,f21,f22;
  #pragma unroll
  for (int q = 0; q < NQ; ++q) {
    const float* m = &lds[(q * TPB + tid) * 9];
    f00[q]=m[0]; f01[q]=m[1]; f02[q]=m[2];
    f10[q]=m[3]; f11[q]=m[4]; f12[q]=m[5];
    f20[q]=m[6]; f21[q]=m[7]; f22[q]=m[8];
  }

  // ---- U construction: u0 = Fv0/|Fv0|; u1 = GS; u2 = u0 x u1 (sign-fixed) ----
  v4 w0x = f00*v00 + f01*v10 + f02*v20;
  v4 w0y = f10*v00 + f11*v10 + f12*v20;
  v4 w0z = f20*v00 + f21*v10 + f22*v20;
  v4 n0sq = w0x*w0x + w0y*w0y + w0z*w0z;
  v4 inv0 = rsq4(vmax(n0sq, V4(1e-30f)));
  v4 sig0 = n0sq * inv0;                 // = sqrt(n0sq)
  v4 u0x = w0x*inv0, u0y = w0y*inv0, u0z = w0z*inv0;

  v4 w1x = f00*v01 + f01*v11 + f02*v21;
  v4 w1y = f10*v01 + f11*v11 + f12*v21;
  v4 w1z = f20*v01 + f21*v11 + f22*v21;
  v4 sig1 = sqt4(w1x*w1x + w1y*w1y + w1z*w1z);   // pre-GS norm = sigma1
  v4 d01 = w1x*u0x + w1y*u0y + w1z*u0z;
  w1x = w1x - d01*u0x; w1y = w1y - d01*u0y; w1z = w1z - d01*u0z;
  v4 n1sq = w1x*w1x + w1y*w1y + w1z*w1z;
  v4 inv1 = rsq4(vmax(n1sq, V4(1e-30f)));
  v4 u1x = w1x*inv1, u1y = w1y*inv1, u1z = w1z*inv1;

  v4 u2x = u0y*u1z - u0z*u1y;
  v4 u2y = u0z*u1x - u0x*u1z;
  v4 u2z = u0x*u1y - u0y*u1x;
  v4 w2x = f00*v02 + f01*v12 + f02*v22;
  v4 w2y = f10*v02 + f11*v12 + f12*v22;
  v4 w2z = f20*v02 + f21*v12 + f22*v22;
  v4 s2d = u2x*w2x + u2y*w2y + u2z*w2z;
  v4i _neg = s2d < V4(0.0f);
  v4 sg = vsel(_neg, V4(-1.0f), V4(1.0f));
  v4 sig2 = s2d * sg;
  u2x = u2x * sg; u2y = u2y * sg; u2z = u2z * sg;

  // ---- von-Mises return mapping, base-2 internally ----
  v4 c0 = vmax(sig0, V4(0.01f));
  v4 c1 = vmax(sig1, V4(0.01f));
  v4 c2 = vmax(sig2, V4(0.01f));
  v4 e0 = lg24(c0), e1 = lg24(c1), e2 = lg24(c2);
  v4 m3 = (e0 + e1 + e2) * (1.0f / 3.0f);
  v4 b0 = e0 - m3, b1 = e1 - m3, b2 = e2 - m3;
  // ||dev eps||_ln = ln2 * ||b||_log2 ; +NORM_EPS in ln units
  v4 bn = sqt4(b0*b0 + b1*b1 + b2*b2) * 0.69314718f + V4(1e-5f);
  v4 r = vmax(bn - qy, V4(0.0f)) * rcp4(bn);  // 0 if elastic
  c0 = ex24(e0 - r * b0);
  c1 = ex24(e1 - r * b1);
  c2 = ex24(e2 - r * b2);

  // ---- out = sum_i c_i u_i v_i^T ----
  v4 a0x = c0*u0x, a0y = c0*u0y, a0z = c0*u0z;
  v4 a1x = c1*u1x, a1y = c1*u1y, a1z = c1*u1z;
  v4 a2x = c2*u2x, a2y = c2*u2y, a2z = c2*u2z;

  v4 o00 = a0x*v00 + a1x*v01 + a2x*v02;
  v4 o01 = a0x*v10 + a1x*v11 + a2x*v12;
  v4 o02 = a0x*v20 + a1x*v21 + a2x*v22;
  v4 o10 = a0y*v00 + a1y*v01 + a2y*v02;
  v4 o11 = a0y*v10 + a1y*v11 + a2y*v12;
  v4 o12 = a0y*v20 + a1y*v21 + a2y*v22;
  v4 o20 = a0z*v00 + a1z*v01 + a2z*v02;
  v4 o21 = a0z*v10 + a1z*v11 + a2z*v12;
  v4 o22 = a0z*v20 + a1z*v21 + a2z*v22;

  #pragma unroll
  for (int q = 0; q < NQ; ++q) {
    if (blockBase + q * TPB + tid < nmat) {
      float* m = &lds[(q * TPB + tid) * 9];
      m[0]=o00[q]; m[1]=o01[q]; m[2]=o02[q];
      m[3]=o10[q]; m[4]=o11[q]; m[5]=o12[q];
      m[6]=o20[q]; m[7]=o21[q]; m[8]=o22[q];
    }
  }
  __syncthreads();

  // coalesced LDS -> global store, float4-wide
  {
    float4* g4 = (float4*)(out + gbase);
    const float4* l4 = (const float4*)lds;
    #pragma unroll
    for (int k = 0; k < 9; ++k) {
      int i4 = k * TPB + tid;
      if (i4 < nfl4) g4[i4] = l4[i4];
    }
    int i = (nfl & ~3) + tid;
    if (i < nfl) out[gbase + i] = lds[i];
  }
}

extern "C" void kernel_launch(void* const* d_in, const int* in_sizes, int n_in,
                              void* d_out, int out_size, void* d_ws, size_t ws_size,
                              hipStream_t stream) {
  const float* F     = (const float*)d_in[0];
  const float* p_yml = (const float*)d_in[1];
  const float* p_nu  = (const float*)d_in[2];
  const float* p_ys  = (const float*)d_in[3];
  float* out = (float*)d_out;

  const int nmat = in_sizes[0] / 9;
  const int nblocks = (nmat + MPB - 1) / MPB;
  hipLaunchKernelGGL(plastic_svd_kernel, dim3(nblocks), dim3(TPB), 0, stream,
                     F, p_yml, p_nu, p_ys, out, nmat);
}